// Round 7
// baseline (636.238 us; speedup 1.0000x reference)
//
#include <hip/hip_runtime.h>
#include <hip/hip_bf16.h>
#include <hip/hip_fp16.h>
#include <math.h>

#define NN 512
#define HH 32
#define PP 64
#define EE 512

// ---------------------------------------------------------------------------
// Kernel 0: prep derived params. One block per head h (32 blocks, 256 thr).
// ---------------------------------------------------------------------------
__global__ __launch_bounds__(256)
void prep_kernel(const float* __restrict__ Wv, const float* __restrict__ Wf,
                 const float* __restrict__ Wb, const float* __restrict__ pg,
                 const float* __restrict__ pb, const float* __restrict__ bbv,
                 float* __restrict__ Wu, float* __restrict__ Wbp,
                 float* __restrict__ s1, float* __restrict__ s2) {
    const int h = blockIdx.x;
    const int t = threadIdx.x;
    __shared__ float sh1[64], sh2[64];
#pragma unroll
    for (int r = 0; r < 2; ++r) {
        const int e = r * 256 + t;
        float acc = 0.f;
#pragma unroll
        for (int d = 0; d < 16; ++d)
            acc += Wf[h * 16 + d] * Wv[(size_t)(h * 16 + d) * EE + e];
        Wu[h * EE + e] = acc;
    }
    if (t < 64) {
        const float wb = Wb[h * PP + t];
        Wbp[h * PP + t] = pg[t] * wb;
        sh1[t] = pg[t] * wb;
        sh2[t] = pb[t] * wb;
    }
    __syncthreads();
    if (t == 0) {
        float a = 0.f, s = 0.f;
#pragma unroll
        for (int p = 0; p < 64; ++p) { a += sh1[p]; s += sh2[p]; }
        s1[h] = a;
        s2[h] = s + bbv[h];
    }
}

// ---------------------------------------------------------------------------
// Kernel 1: LayerNorm(query) -> xq   (2048 rows of 512)
// ---------------------------------------------------------------------------
__global__ __launch_bounds__(256)
void ln_query_kernel(const float* __restrict__ x, const float* __restrict__ g,
                     const float* __restrict__ b, float* __restrict__ xq) {
    const int row = blockIdx.x;
    const int t = threadIdx.x;
    const int wave = t >> 6, lane = t & 63;
    const float2 v = ((const float2*)(x + (size_t)row * EE))[t];
    float s = v.x + v.y;
    float ss = v.x * v.x + v.y * v.y;
#pragma unroll
    for (int o = 32; o > 0; o >>= 1) {
        s += __shfl_xor(s, o, 64);
        ss += __shfl_xor(ss, o, 64);
    }
    __shared__ float rs[4], rss[4];
    if (lane == 0) { rs[wave] = s; rss[wave] = ss; }
    __syncthreads();
    s = rs[0] + rs[1] + rs[2] + rs[3];
    ss = rss[0] + rss[1] + rss[2] + rss[3];
    const float mu = s * (1.f / 512.f);
    const float var = ss * (1.f / 512.f) - mu * mu;
    const float istd = rsqrtf(var + 1e-5f);
    const float2 gg = ((const float2*)g)[t];
    const float2 bb2 = ((const float2*)b)[t];
    float2 o;
    o.x = (v.x - mu) * istd * gg.x + bb2.x;
    o.y = (v.y - mu) * istd * gg.y + bb2.y;
    ((float2*)(xq + (size_t)row * EE))[t] = o;
}

// ---------------------------------------------------------------------------
// Kernel 2: projections GEMM.  C[2048 x 1056] = xq @ [Wq|Wk|Wu]^T
//   cols [0,512)    -> q scaled 0.25, stored [row][e]
//   cols [512,1024) -> k stored kt[c][h][dp][n][2]   (R4 float2 layout —
//                      float4 layout raised attn VGPR 64->68, halved occ)
//   cols [1024,1056)-> u stored uT[c][h][n]
// 32x32 tiles, BK=32, 2x2 micro-tile (R4's; 2112 blocks, best residual).
// ---------------------------------------------------------------------------
__global__ __launch_bounds__(256)
void proj_gemm_kernel(const float* __restrict__ xq, const float* __restrict__ Wq,
                      const float* __restrict__ Wk, const float* __restrict__ Wu,
                      float* __restrict__ qo, float* __restrict__ kt,
                      float* __restrict__ uT) {
    __shared__ float As[32][33];   // [k][row]
    __shared__ float Bs[32][33];   // [k][col]
    const int t = threadIdx.x;
    const int row0 = blockIdx.x * 32;
    const int col0 = blockIdx.y * 32;
    const int tx = t & 15, ty = t >> 4;
    const int lr = t >> 3;
    const int lk4 = (t & 7) * 4;

    const int gcb = col0 + lr;
    const float* wrow;
    if (gcb < 512) wrow = Wq + (size_t)gcb * EE;
    else if (gcb < 1024) wrow = Wk + (size_t)(gcb - 512) * EE;
    else wrow = Wu + (size_t)(gcb - 1024) * EE;
    const float* arow = xq + (size_t)(row0 + lr) * EE;

    float a00 = 0.f, a01 = 0.f, a10 = 0.f, a11 = 0.f;
#pragma unroll 1
    for (int k0 = 0; k0 < EE; k0 += 32) {
        const float4 av = *(const float4*)(arow + k0 + lk4);
        const float4 bv = *(const float4*)(wrow + k0 + lk4);
        __syncthreads();
        As[lk4 + 0][lr] = av.x; As[lk4 + 1][lr] = av.y;
        As[lk4 + 2][lr] = av.z; As[lk4 + 3][lr] = av.w;
        Bs[lk4 + 0][lr] = bv.x; Bs[lk4 + 1][lr] = bv.y;
        Bs[lk4 + 2][lr] = bv.z; Bs[lk4 + 3][lr] = bv.w;
        __syncthreads();
#pragma unroll
        for (int kk = 0; kk < 32; ++kk) {
            const float2 a = *(const float2*)&As[kk][ty * 2];
            const float2 b = *(const float2*)&Bs[kk][tx * 2];
            a00 += a.x * b.x; a01 += a.x * b.y;
            a10 += a.y * b.x; a11 += a.y * b.y;
        }
    }

    float accv[2][2] = {{a00, a01}, {a10, a11}};
#pragma unroll
    for (int r = 0; r < 2; ++r) {
        const int grow = row0 + ty * 2 + r;
        const int c = grow >> 9, n = grow & 511;
#pragma unroll
        for (int cc = 0; cc < 2; ++cc) {
            const int gc = col0 + tx * 2 + cc;
            const float v = accv[r][cc];
            if (gc < 512) {
                qo[(size_t)grow * EE + gc] = v * 0.25f;
            } else if (gc < 1024) {
                const int e = gc - 512;
                const int h = e >> 4, d = e & 15;
                kt[((((size_t)c * HH + h) * 8 + (d >> 1)) * NN + n) * 2 + (d & 1)] = v;
            } else {
                const int h = gc - 1024;
                uT[((size_t)c * HH + h) * NN + n] = v;
            }
        }
    }
}

// ---------------------------------------------------------------------------
// Kernel 3: fused attention+force — R4 structure (512 thr, 4 compile-time
// head-groups of 8, scalar Wbp loads, float2 kt reads, 64 VGPR no-spill)
// with ONE change: exp(logits) stored in LDS as fp16 -> 32 KB attn array ->
// 4 blocks/CU instead of 2 (occupancy 43% -> ~90%).
// INVARIANTS (violating either cost 2-4x in R5/R6):
//  - head-group index g must be compile-time (wave-uniform Wbp -> s_loads)
//  - VGPR must stay <= 64 (waves halve past 64; keep float2 kt loads)
// ---------------------------------------------------------------------------
__global__ __launch_bounds__(512)
void attn_force_kernel(const float* __restrict__ pair, const float* __restrict__ delta,
                       const float* __restrict__ qws, const float* __restrict__ kt,
                       const float* __restrict__ uT, const float* __restrict__ Wbp,
                       const float* __restrict__ s1, const float* __restrict__ s2,
                       float* __restrict__ out) {
    __shared__ __half attn[HH][NN];  // 32 KB: exp(logit)[h][j] in fp16
    __shared__ float invd[HH];
    __shared__ float red[8][3];

    const int t = threadIdx.x;       // = j
    const int wave = t >> 6, lane = t & 63;
    const int bid = blockIdx.x;      // c*512 + i
    const int c = bid >> 9;
    const int i = bid & 511;
    const int j = t;

    const float4* prow = (const float4*)(pair + (((size_t)c * NN + i) * NN + j) * PP);
    const float* qrow = qws + (size_t)bid * EE;               // wave-uniform -> s_load
    const float2* ktc = (const float2*)(kt + (size_t)c * HH * 8 * NN * 2);

    float mu = 0.f, istd = 0.f;
#pragma unroll 1
    for (int g = 0; g < 4; ++g) {
        float l8[8] = {0.f, 0.f, 0.f, 0.f, 0.f, 0.f, 0.f, 0.f};
        float s = 0.f, ss = 0.f;
#pragma unroll
        for (int x = 0; x < 16; ++x) {
            const float4 pv = prow[x];
            if (g == 0) {
                s += pv.x + pv.y + pv.z + pv.w;
                ss += pv.x * pv.x + pv.y * pv.y + pv.z * pv.z + pv.w * pv.w;
            }
#pragma unroll
            for (int hh = 0; hh < 8; ++hh) {
                const float4 w = *(const float4*)(Wbp + (g * 8 + hh) * PP + x * 4);
                l8[hh] += pv.x * w.x + pv.y * w.y + pv.z * w.z + pv.w * w.w;
            }
        }
        if (g == 0) {
            mu = s * (1.f / 64.f);
            const float var = ss * (1.f / 64.f) - mu * mu;
            istd = rsqrtf(var + 1e-5f);
        }
#pragma unroll
        for (int hh = 0; hh < 8; ++hh) {
            const int h = g * 8 + hh;
            float qk = 0.f;
#pragma unroll
            for (int dp = 0; dp < 8; ++dp) {
                const float2 kv = ktc[((size_t)h * 8 + dp) * NN + j];
                const float2 qv = *(const float2*)(qrow + h * 16 + dp * 2);
                qk += kv.x * qv.x + kv.y * qv.y;
            }
            attn[h][j] = __float2half_rn(
                __expf(qk + istd * (l8[hh] - mu * s1[h]) + s2[h]));
        }
    }
    __syncthreads();

    // ---- softmax denominators: each wave owns heads [wave*4, wave*4+4) ----
#pragma unroll
    for (int q = 0; q < 4; ++q) {
        const int h = wave * 4 + q;
        float v = 0.f;
#pragma unroll
        for (int x = 0; x < 8; ++x) v += __half2float(attn[h][x * 64 + lane]);
#pragma unroll
        for (int o = 32; o > 0; o >>= 1) v += __shfl_xor(v, o, 64);
        if (lane == 0) invd[h] = 1.f / v;
    }
    __syncthreads();

    // ---- per-j weight, then force reduction ----
    float w = 0.f;
#pragma unroll
    for (int h = 0; h < HH; ++h)
        w += __half2float(attn[h][j]) * invd[h] * uT[((size_t)c * HH + h) * NN + j];

    const float* d3 = delta + (((size_t)c * NN + i) * NN + j) * 3;
    float fx = w * d3[0], fy = w * d3[1], fz = w * d3[2];
#pragma unroll
    for (int o = 32; o > 0; o >>= 1) {
        fx += __shfl_xor(fx, o, 64);
        fy += __shfl_xor(fy, o, 64);
        fz += __shfl_xor(fz, o, 64);
    }
    if (lane == 0) { red[wave][0] = fx; red[wave][1] = fy; red[wave][2] = fz; }
    __syncthreads();
    if (t == 0) {
        float ox = 0.f, oy = 0.f, oz = 0.f;
#pragma unroll
        for (int w8 = 0; w8 < 8; ++w8) { ox += red[w8][0]; oy += red[w8][1]; oz += red[w8][2]; }
        out[(size_t)bid * 3 + 0] = ox;
        out[(size_t)bid * 3 + 1] = oy;
        out[(size_t)bid * 3 + 2] = oz;
    }
}

// ---------------------------------------------------------------------------
extern "C" void kernel_launch(void* const* d_in, const int* in_sizes, int n_in,
                              void* d_out, int out_size, void* d_ws, size_t ws_size,
                              hipStream_t stream) {
    const float* query   = (const float*)d_in[0];
    const float* pair    = (const float*)d_in[1];
    const float* delta   = (const float*)d_in[2];
    const float* ln_q_g  = (const float*)d_in[3];
    const float* ln_q_b  = (const float*)d_in[4];
    const float* ln_p_g  = (const float*)d_in[5];
    const float* ln_p_b  = (const float*)d_in[6];
    const float* Wq      = (const float*)d_in[7];
    const float* Wk      = (const float*)d_in[8];
    const float* Wv      = (const float*)d_in[9];
    const float* Wb      = (const float*)d_in[10];
    const float* bbv     = (const float*)d_in[11];
    const float* Wf      = (const float*)d_in[12];
    float* out = (float*)d_out;

    float* ws = (float*)d_ws;
    float* xq  = ws;                        // 2048*512
    float* qws = xq + 2048 * 512;           // 2048*512
    float* kt  = qws + 2048 * 512;          // 2048*512
    float* uT  = kt + 2048 * 512;           // 4*32*512
    float* Wu  = uT + 4 * 32 * 512;         // 32*512
    float* Wbp = Wu + 32 * 512;             // 32*64
    float* s1  = Wbp + 32 * 64;             // 32
    float* s2  = s1 + 32;                   // 32

    prep_kernel<<<32, 256, 0, stream>>>(Wv, Wf, Wb, ln_p_g, ln_p_b, bbv,
                                        Wu, Wbp, s1, s2);
    ln_query_kernel<<<2048, 256, 0, stream>>>(query, ln_q_g, ln_q_b, xq);
    proj_gemm_kernel<<<dim3(64, 33), 256, 0, stream>>>(xq, Wq, Wk, Wu,
                                                       qws, kt, uT);
    attn_force_kernel<<<2048, 512, 0, stream>>>(pair, delta, qws, kt, uT,
                                                Wbp, s1, s2, out);
}